// Round 9
// baseline (212.241 us; speedup 1.0000x reference)
//
#include <hip/hip_runtime.h>

#define N_NODES 100000
#define N_EDGES 1600000
#define IN_C 32
#define HID_C 64
#define OUT_C 32

#define EPB 1024                                 // edges per hist/place block
#define NBLK ((N_EDGES + EPB - 1) / EPB)         // 1563
#define BSH 8                                    // 256 nodes per bucket
#define BKN (1 << BSH)
#define NB ((N_NODES + BKN - 1) / BKN)           // 391

// ---- pass A: per-block bucket histogram (LDS only; no global atomics) ---
__global__ __launch_bounds__(256) void bucket_hist_kernel(
    const int* __restrict__ dst, int* __restrict__ gh) {
    __shared__ int lh[NB];
    for (int i = threadIdx.x; i < NB; i += 256) lh[i] = 0;
    __syncthreads();
    int base = blockIdx.x * EPB;
#pragma unroll
    for (int j = 0; j < EPB / 256; ++j) {
        int e = base + j * 256 + threadIdx.x;
        if (e < N_EDGES) atomicAdd(&lh[dst[e] >> BSH], 1);
    }
    __syncthreads();
    for (int i = threadIdx.x; i < NB; i += 256)
        gh[i * NBLK + blockIdx.x] = lh[i];
}

// ---- pass B: per-bucket exclusive scan of gh across blocks + totals -----
__global__ __launch_bounds__(256) void bucket_scan_kernel(
    int* __restrict__ gh, int* __restrict__ btot) {
    int b = blockIdx.x;
    int t = threadIdx.x;
    __shared__ int ssum[256];
    int v[7];
    int base = t * 7;
    int s = 0;
#pragma unroll
    for (int j = 0; j < 7; ++j) {
        int idx = base + j;
        int val = (idx < NBLK) ? gh[b * NBLK + idx] : 0;
        v[j] = s;
        s += val;
    }
    ssum[t] = s;
    __syncthreads();
    for (int o = 1; o < 256; o <<= 1) {
        int val = (t >= o) ? ssum[t - o] : 0;
        __syncthreads();
        ssum[t] += val;
        __syncthreads();
    }
    int texcl = ssum[t] - s;
#pragma unroll
    for (int j = 0; j < 7; ++j) {
        int idx = base + j;
        if (idx < NBLK) gh[b * NBLK + idx] = texcl + v[j];
    }
    if (t == 255) btot[b] = ssum[255];
}

// ---- pass C: scan bucket totals -> bucket bases (bbase[NB] = N_EDGES) ---
__global__ void base_scan_kernel(const int* __restrict__ btot,
                                 int* __restrict__ bbase) {
    int acc = 0;
    for (int i = 0; i < NB; ++i) { bbase[i] = acc; acc += btot[i]; }
    bbase[NB] = acc;
}

// ---- pass D: place (src,dst) pairs into bucket-sorted tmp ---------------
__global__ __launch_bounds__(256) void bucket_place_kernel(
    const int* __restrict__ src, const int* __restrict__ dst,
    const int* __restrict__ gh, const int* __restrict__ bbase,
    uint2* __restrict__ tmp) {
    __shared__ int cur[NB];
    for (int i = threadIdx.x; i < NB; i += 256)
        cur[i] = bbase[i] + gh[i * NBLK + blockIdx.x];
    __syncthreads();
    int base = blockIdx.x * EPB;
#pragma unroll
    for (int j = 0; j < EPB / 256; ++j) {
        int e = base + j * 256 + threadIdx.x;
        if (e < N_EDGES) {
            int d = dst[e];
            int slot = atomicAdd(&cur[d >> BSH], 1);
            tmp[slot] = make_uint2((unsigned)src[e], (unsigned)d);
        }
    }
}

// ---- pass E: per-bucket counts + rowptr + perm (all LDS, no global atomics)
__global__ __launch_bounds__(512) void count_place_kernel(
    const uint2* __restrict__ tmp, const int* __restrict__ bbase,
    int* __restrict__ counts, int* __restrict__ rowptr,
    int* __restrict__ perm) {
    __shared__ int lcnt[BKN];
    __shared__ int sscan[BKN];
    __shared__ int cur[BKN];
    int b = blockIdx.x;
    int tid = threadIdx.x;
    int start = bbase[b], end = bbase[b + 1];
    if (tid < BKN) lcnt[tid] = 0;
    __syncthreads();
    for (int i = start + tid; i < end; i += 512)
        atomicAdd(&lcnt[tmp[i].y & (BKN - 1)], 1);
    __syncthreads();
    if (tid < BKN) sscan[tid] = lcnt[tid];
    __syncthreads();
    for (int o = 1; o < BKN; o <<= 1) {
        int v = 0;
        if (tid < BKN && tid >= o) v = sscan[tid - o];
        __syncthreads();
        if (tid < BKN) sscan[tid] += v;
        __syncthreads();
    }
    if (tid < BKN) {
        int excl = sscan[tid] - lcnt[tid] + start;
        cur[tid] = excl;
        int n = (b << BSH) + tid;
        if (n < N_NODES) { rowptr[n] = excl; counts[n] = lcnt[tid]; }
    }
    __syncthreads();
    for (int i = start + tid; i < end; i += 512) {
        uint2 p = tmp[i];
        int slot = atomicAdd(&cur[p.y & (BKN - 1)], 1);
        perm[slot] = (int)p.x;
    }
}

// ---- gathers: one wave per node, 8 edges x float4 in flight -------------
__global__ __launch_bounds__(256) void gather_mean_kernel(
    const float* __restrict__ feat, const int* __restrict__ rowptr,
    const int* __restrict__ counts, const int* __restrict__ perm,
    float* __restrict__ meanout) {
    int lane = threadIdx.x & 63;
    int wid = threadIdx.x >> 6;
    int n = blockIdx.x * 4 + wid;
    if (n >= N_NODES) return;
    int g = lane >> 3;
    int q = lane & 7;
    int start = rowptr[n];
    int cnt = counts[n];
    int end = start + cnt;
    float4 acc = make_float4(0.f, 0.f, 0.f, 0.f);
    for (int i = start + g; i < end; i += 8) {
        int idx = perm[i];
        float4 v = ((const float4*)&feat[(long long)idx * 32])[q];
        acc.x += v.x; acc.y += v.y; acc.z += v.z; acc.w += v.w;
    }
#pragma unroll
    for (int off = 8; off < 64; off <<= 1) {
        acc.x += __shfl_xor(acc.x, off, 64);
        acc.y += __shfl_xor(acc.y, off, 64);
        acc.z += __shfl_xor(acc.z, off, 64);
        acc.w += __shfl_xor(acc.w, off, 64);
    }
    if (g == 0) {
        float inv = 1.0f / fmaxf((float)cnt, 1.0f);
        ((float4*)&meanout[(long long)n * 32])[q] =
            make_float4(acc.x * inv, acc.y * inv, acc.z * inv, acc.w * inv);
    }
}

__global__ __launch_bounds__(256) void gather_final_kernel(
    const float* __restrict__ t, const int* __restrict__ rowptr,
    const int* __restrict__ counts, const int* __restrict__ perm,
    const float* __restrict__ r, float* __restrict__ out) {
    int lane = threadIdx.x & 63;
    int wid = threadIdx.x >> 6;
    int n = blockIdx.x * 4 + wid;
    if (n >= N_NODES) return;
    int g = lane >> 3;
    int q = lane & 7;
    int start = rowptr[n];
    int cnt = counts[n];
    int end = start + cnt;
    float4 acc = make_float4(0.f, 0.f, 0.f, 0.f);
    for (int i = start + g; i < end; i += 8) {
        int idx = perm[i];
        float4 v = ((const float4*)&t[(long long)idx * 32])[q];
        acc.x += v.x; acc.y += v.y; acc.z += v.z; acc.w += v.w;
    }
#pragma unroll
    for (int off = 8; off < 64; off <<= 1) {
        acc.x += __shfl_xor(acc.x, off, 64);
        acc.y += __shfl_xor(acc.y, off, 64);
        acc.z += __shfl_xor(acc.z, off, 64);
        acc.w += __shfl_xor(acc.w, off, 64);
    }
    if (g == 0) {
        float inv = 1.0f / fmaxf((float)cnt, 1.0f);
        float4 rv = ((const float4*)&r[(long long)n * 32])[q];
        ((float4*)&out[(long long)n * 32])[q] =
            make_float4(acc.x * inv + rv.x, acc.y * inv + rv.y,
                        acc.z * inv + rv.z, acc.w * inv + rv.w);
    }
}

// ---- per-node dense transform: 4 threads/node x 4 nodes/thread ----------
// lane = slot*4 + sub; slot s owns nodes {base+s, base+64+s, +128+s, +192+s}.
// Weight LDS reads (8 ds_read_b128 per j) are amortized over 4 nodes ->
// ds_read count per CU drops 4x vs round 8 (the measured bottleneck).
// Layer 1: sub splits c-reduction (8 floats); h completed via 2x quad shfl.
// Layer 2: sub owns k-chunk of 8; W2 transposed, stride 36 (conflict-free).
#define W2S 36
#define NPT 4
__global__ __launch_bounds__(256) void node_transform_kernel(
    const float* __restrict__ x, const float* __restrict__ mean1,
    const float* __restrict__ W1l, const float* __restrict__ W1r,
    const float* __restrict__ b1, const float* __restrict__ W2l,
    const float* __restrict__ W2r, const float* __restrict__ b2,
    float* __restrict__ t, float* __restrict__ rout)
{
    __shared__ float sW1l[HID_C * IN_C];     // [j][c]
    __shared__ float sW1r[HID_C * IN_C];
    __shared__ float sW2lT[HID_C * W2S];     // [j][k], stride 36
    __shared__ float sW2rT[HID_C * W2S];
    __shared__ float sb1[HID_C];
    __shared__ float sb2[OUT_C];

    for (int i = threadIdx.x; i < HID_C * IN_C; i += 256) {
        sW1l[i] = W1l[i];
        sW1r[i] = W1r[i];
    }
    for (int i = threadIdx.x; i < OUT_C * HID_C; i += 256) {
        int k = i >> 6;
        int j = i & 63;
        sW2lT[j * W2S + k] = W2l[i];
        sW2rT[j * W2S + k] = W2r[i];
    }
    if (threadIdx.x < HID_C) sb1[threadIdx.x] = b1[threadIdx.x];
    if (threadIdx.x < OUT_C) sb2[threadIdx.x] = b2[threadIdx.x];
    __syncthreads();

    int sub = threadIdx.x & 3;
    int slot = threadIdx.x >> 2;             // 0..63
    int nbase = blockIdx.x * 256;
    int c0 = sub * 8;
    int k0 = sub * 8;

    float4 xq[NPT][2], mq[NPT][2];
#pragma unroll
    for (int i = 0; i < NPT; ++i) {
        int n = nbase + i * 64 + slot;
        if (n < N_NODES) {
            const float4* xp = (const float4*)&x[(long long)n * IN_C + c0];
            const float4* mp = (const float4*)&mean1[(long long)n * IN_C + c0];
            xq[i][0] = xp[0]; xq[i][1] = xp[1];
            mq[i][0] = mp[0]; mq[i][1] = mp[1];
        } else {
            xq[i][0] = xq[i][1] = mq[i][0] = mq[i][1] =
                make_float4(0.f, 0.f, 0.f, 0.f);
        }
    }

    float tacc[NPT][8], racc[NPT][8];
#pragma unroll
    for (int i = 0; i < NPT; ++i)
#pragma unroll
        for (int k = 0; k < 8; ++k) { tacc[i][k] = 0.f; racc[i][k] = sb2[k0 + k]; }

#pragma unroll 2
    for (int j = 0; j < HID_C; ++j) {
        const float4* wl = (const float4*)&sW1l[j * IN_C + c0];
        const float4* wr = (const float4*)&sW1r[j * IN_C + c0];
        float4 l0 = wl[0], l1 = wl[1];
        float4 r0 = wr[0], r1 = wr[1];
        const float4* w2l = (const float4*)&sW2lT[j * W2S + k0];
        const float4* w2r = (const float4*)&sW2rT[j * W2S + k0];
        float4 a0 = w2l[0], a1 = w2l[1];
        float4 b0 = w2r[0], b1v = w2r[1];
        float sb1j = sb1[j];

#pragma unroll
        for (int i = 0; i < NPT; ++i) {
            float p = mq[i][0].x * l0.x + mq[i][0].y * l0.y
                    + mq[i][0].z * l0.z + mq[i][0].w * l0.w
                    + mq[i][1].x * l1.x + mq[i][1].y * l1.y
                    + mq[i][1].z * l1.z + mq[i][1].w * l1.w
                    + xq[i][0].x * r0.x + xq[i][0].y * r0.y
                    + xq[i][0].z * r0.z + xq[i][0].w * r0.w
                    + xq[i][1].x * r1.x + xq[i][1].y * r1.y
                    + xq[i][1].z * r1.z + xq[i][1].w * r1.w;
            p += __shfl_xor(p, 1, 64);
            p += __shfl_xor(p, 2, 64);
            float hj = fmaxf(p + sb1j, 0.0f);

            tacc[i][0] += hj * a0.x; tacc[i][1] += hj * a0.y;
            tacc[i][2] += hj * a0.z; tacc[i][3] += hj * a0.w;
            tacc[i][4] += hj * a1.x; tacc[i][5] += hj * a1.y;
            tacc[i][6] += hj * a1.z; tacc[i][7] += hj * a1.w;
            racc[i][0] += hj * b0.x; racc[i][1] += hj * b0.y;
            racc[i][2] += hj * b0.z; racc[i][3] += hj * b0.w;
            racc[i][4] += hj * b1v.x; racc[i][5] += hj * b1v.y;
            racc[i][6] += hj * b1v.z; racc[i][7] += hj * b1v.w;
        }
    }

#pragma unroll
    for (int i = 0; i < NPT; ++i) {
        int n = nbase + i * 64 + slot;
        if (n < N_NODES) {
            float4* tp = (float4*)&t[(long long)n * OUT_C + k0];
            float4* rp = (float4*)&rout[(long long)n * OUT_C + k0];
            tp[0] = make_float4(tacc[i][0], tacc[i][1], tacc[i][2], tacc[i][3]);
            tp[1] = make_float4(tacc[i][4], tacc[i][5], tacc[i][6], tacc[i][7]);
            rp[0] = make_float4(racc[i][0], racc[i][1], racc[i][2], racc[i][3]);
            rp[1] = make_float4(racc[i][4], racc[i][5], racc[i][6], racc[i][7]);
        }
    }
}

// ---- launch -------------------------------------------------------------

extern "C" void kernel_launch(void* const* d_in, const int* in_sizes, int n_in,
                              void* d_out, int out_size, void* d_ws, size_t ws_size,
                              hipStream_t stream) {
    const float* x   = (const float*)d_in[0];
    const float* W1l = (const float*)d_in[1];
    const float* W1r = (const float*)d_in[2];
    const float* b1  = (const float*)d_in[3];
    const float* W2l = (const float*)d_in[4];
    const float* W2r = (const float*)d_in[5];
    const float* b2  = (const float*)d_in[6];
    const int*   ei  = (const int*)d_in[7];   // [2, N_EDGES]
    const int* src = ei;
    const int* dst = ei + N_EDGES;

    char* ws = (char*)d_ws;
    int*   gh     = (int*)ws;                ws += (size_t)NB * NBLK * 4;
    int*   btot   = (int*)ws;                ws += (size_t)(NB + 8) * 4;
    int*   bbase  = (int*)ws;                ws += (size_t)(NB + 8) * 4;
    int*   counts = (int*)ws;                ws += (size_t)N_NODES * 4;
    int*   rowptr = (int*)ws;                ws += (size_t)N_NODES * 4;
    int*   perm   = (int*)ws;                ws += (size_t)N_EDGES * 4;
    uint2* tmp    = (uint2*)ws;              ws += (size_t)N_EDGES * 8;
    // mean1 aliases tmp: tmp is dead after count_place_kernel; mean1 written after.
    float* mean1  = (float*)tmp;
    float* t      = (float*)ws;              ws += (size_t)N_NODES * OUT_C * 4;
    float* r      = (float*)ws;              ws += (size_t)N_NODES * OUT_C * 4;

    dim3 blk(256);
    int ggrid = (N_NODES + 3) / 4;

    bucket_hist_kernel<<<NBLK, blk, 0, stream>>>(dst, gh);
    bucket_scan_kernel<<<NB, blk, 0, stream>>>(gh, btot);
    base_scan_kernel<<<1, 1, 0, stream>>>(btot, bbase);
    bucket_place_kernel<<<NBLK, blk, 0, stream>>>(src, dst, gh, bbase, tmp);
    count_place_kernel<<<NB, dim3(512), 0, stream>>>(tmp, bbase, counts, rowptr, perm);

    gather_mean_kernel<<<ggrid, blk, 0, stream>>>(x, rowptr, counts, perm, mean1);
    node_transform_kernel<<<(N_NODES + 255) / 256, blk, 0, stream>>>(
        x, mean1, W1l, W1r, b1, W2l, W2r, b2, t, r);
    gather_final_kernel<<<ggrid, blk, 0, stream>>>(t, rowptr, counts, perm, r,
                                                   (float*)d_out);
}

// Round 10
// 169.317 us; speedup vs baseline: 1.2535x; 1.2535x over previous
//
#include <hip/hip_runtime.h>

#define N_NODES 100000
#define N_EDGES 1600000
#define IN_C 32
#define HID_C 64
#define OUT_C 32

#define EPB 1024                                 // edges per hist/place block
#define NBLK ((N_EDGES + EPB - 1) / EPB)         // 1563
#define BSH 8                                    // 256 nodes per bucket
#define BKN (1 << BSH)
#define NB ((N_NODES + BKN - 1) / BKN)           // 391

typedef __attribute__((ext_vector_type(8))) short bf16x8;
typedef __attribute__((ext_vector_type(8))) unsigned short u16x8;
typedef __attribute__((ext_vector_type(4))) float f32x4;

__device__ __forceinline__ unsigned short f2bf(float f) {
    unsigned u = __float_as_uint(f);
    return (unsigned short)((u + 0x7fffu + ((u >> 16) & 1u)) >> 16);
}
__device__ __forceinline__ float bf2f(unsigned short h) {
    return __uint_as_float((unsigned)h << 16);
}

// ---- casts --------------------------------------------------------------
__global__ __launch_bounds__(256) void cast_x_kernel(
    const float* __restrict__ x, ushort* __restrict__ xb) {
    int i = blockIdx.x * 256 + threadIdx.x;          // one thread per 8 floats
    if (i >= N_NODES * IN_C / 8) return;
    const float4* p = (const float4*)&x[(size_t)i * 8];
    float4 a = p[0], b = p[1];
    u16x8 o;
    o[0] = f2bf(a.x); o[1] = f2bf(a.y); o[2] = f2bf(a.z); o[3] = f2bf(a.w);
    o[4] = f2bf(b.x); o[5] = f2bf(b.y); o[6] = f2bf(b.z); o[7] = f2bf(b.w);
    *(u16x8*)&xb[(size_t)i * 8] = o;
}

__global__ void cast_w_kernel(const float* __restrict__ w1l,
                              const float* __restrict__ w1r,
                              const float* __restrict__ w2l,
                              const float* __restrict__ w2r,
                              ushort* __restrict__ wb) {
    for (int i = threadIdx.x; i < 8192; i += 256) {
        float v;
        if (i < 2048) v = w1l[i];
        else if (i < 4096) v = w1r[i - 2048];
        else if (i < 6144) v = w2l[i - 4096];
        else v = w2r[i - 6144];
        wb[i] = f2bf(v);
    }
}

// ---- pass A: per-block bucket histogram (LDS only) ----------------------
__global__ __launch_bounds__(256) void bucket_hist_kernel(
    const int* __restrict__ dst, int* __restrict__ gh) {
    __shared__ int lh[NB];
    for (int i = threadIdx.x; i < NB; i += 256) lh[i] = 0;
    __syncthreads();
    int base = blockIdx.x * EPB;
#pragma unroll
    for (int j = 0; j < EPB / 256; ++j) {
        int e = base + j * 256 + threadIdx.x;
        if (e < N_EDGES) atomicAdd(&lh[dst[e] >> BSH], 1);
    }
    __syncthreads();
    for (int i = threadIdx.x; i < NB; i += 256)
        gh[i * NBLK + blockIdx.x] = lh[i];
}

// ---- pass B: per-bucket exclusive scan of gh across blocks + totals -----
__global__ __launch_bounds__(256) void bucket_scan_kernel(
    int* __restrict__ gh, int* __restrict__ btot) {
    int b = blockIdx.x;
    int t = threadIdx.x;
    __shared__ int ssum[256];
    int v[7];
    int base = t * 7;
    int s = 0;
#pragma unroll
    for (int j = 0; j < 7; ++j) {
        int idx = base + j;
        int val = (idx < NBLK) ? gh[b * NBLK + idx] : 0;
        v[j] = s;
        s += val;
    }
    ssum[t] = s;
    __syncthreads();
    for (int o = 1; o < 256; o <<= 1) {
        int val = (t >= o) ? ssum[t - o] : 0;
        __syncthreads();
        ssum[t] += val;
        __syncthreads();
    }
    int texcl = ssum[t] - s;
#pragma unroll
    for (int j = 0; j < 7; ++j) {
        int idx = base + j;
        if (idx < NBLK) gh[b * NBLK + idx] = texcl + v[j];
    }
    if (t == 255) btot[b] = ssum[255];
}

// ---- pass C: scan bucket totals -> bucket bases -------------------------
__global__ void base_scan_kernel(const int* __restrict__ btot,
                                 int* __restrict__ bbase) {
    int acc = 0;
    for (int i = 0; i < NB; ++i) { bbase[i] = acc; acc += btot[i]; }
    bbase[NB] = acc;
}

// ---- pass D: place (src,dst) pairs into bucket-sorted tmp ---------------
__global__ __launch_bounds__(256) void bucket_place_kernel(
    const int* __restrict__ src, const int* __restrict__ dst,
    const int* __restrict__ gh, const int* __restrict__ bbase,
    uint2* __restrict__ tmp) {
    __shared__ int cur[NB];
    for (int i = threadIdx.x; i < NB; i += 256)
        cur[i] = bbase[i] + gh[i * NBLK + blockIdx.x];
    __syncthreads();
    int base = blockIdx.x * EPB;
#pragma unroll
    for (int j = 0; j < EPB / 256; ++j) {
        int e = base + j * 256 + threadIdx.x;
        if (e < N_EDGES) {
            int d = dst[e];
            int slot = atomicAdd(&cur[d >> BSH], 1);
            tmp[slot] = make_uint2((unsigned)src[e], (unsigned)d);
        }
    }
}

// ---- pass E: per-bucket counts + rowptr + perm (all LDS) ----------------
__global__ __launch_bounds__(512) void count_place_kernel(
    const uint2* __restrict__ tmp, const int* __restrict__ bbase,
    int* __restrict__ counts, int* __restrict__ rowptr,
    int* __restrict__ perm) {
    __shared__ int lcnt[BKN];
    __shared__ int sscan[BKN];
    __shared__ int cur[BKN];
    int b = blockIdx.x;
    int tid = threadIdx.x;
    int start = bbase[b], end = bbase[b + 1];
    if (tid < BKN) lcnt[tid] = 0;
    __syncthreads();
    for (int i = start + tid; i < end; i += 512)
        atomicAdd(&lcnt[tmp[i].y & (BKN - 1)], 1);
    __syncthreads();
    if (tid < BKN) sscan[tid] = lcnt[tid];
    __syncthreads();
    for (int o = 1; o < BKN; o <<= 1) {
        int v = 0;
        if (tid < BKN && tid >= o) v = sscan[tid - o];
        __syncthreads();
        if (tid < BKN) sscan[tid] += v;
        __syncthreads();
    }
    if (tid < BKN) {
        int excl = sscan[tid] - lcnt[tid] + start;
        cur[tid] = excl;
        int n = (b << BSH) + tid;
        if (n < N_NODES) { rowptr[n] = excl; counts[n] = lcnt[tid]; }
    }
    __syncthreads();
    for (int i = start + tid; i < end; i += 512) {
        uint2 p = tmp[i];
        int slot = atomicAdd(&cur[p.y & (BKN - 1)], 1);
        perm[slot] = (int)p.x;
    }
}

// ---- gather 1: mean of bf16 neighbor rows -> bf16 mean1 -----------------
// one wave per node, 16 edges x ushort8 (16B) in flight
__global__ __launch_bounds__(256) void gather_mean_kernel(
    const ushort* __restrict__ xb, const int* __restrict__ rowptr,
    const int* __restrict__ counts, const int* __restrict__ perm,
    ushort* __restrict__ mb) {
    int lane = threadIdx.x & 63;
    int wid = threadIdx.x >> 6;
    int n = blockIdx.x * 4 + wid;
    if (n >= N_NODES) return;
    int g = lane >> 2;          // edge slot 0..15
    int q = lane & 3;           // channel octet
    int start = rowptr[n];
    int cnt = counts[n];
    int end = start + cnt;
    float acc[8] = {0, 0, 0, 0, 0, 0, 0, 0};
    for (int i = start + g; i < end; i += 16) {
        int idx = perm[i];
        u16x8 v = *(const u16x8*)&xb[(size_t)idx * 32 + q * 8];
#pragma unroll
        for (int k = 0; k < 8; ++k) acc[k] += bf2f(v[k]);
    }
#pragma unroll
    for (int off = 4; off < 64; off <<= 1)
#pragma unroll
        for (int k = 0; k < 8; ++k) acc[k] += __shfl_xor(acc[k], off, 64);
    if (g == 0) {
        float inv = 1.0f / fmaxf((float)cnt, 1.0f);
        u16x8 o;
#pragma unroll
        for (int k = 0; k < 8; ++k) o[k] = f2bf(acc[k] * inv);
        *(u16x8*)&mb[(size_t)n * 32 + q * 8] = o;
    }
}

// ---- gather 2: mean of bf16 t rows + root term -> out (f32) -------------
__global__ __launch_bounds__(256) void gather_final_kernel(
    const ushort* __restrict__ tb, const int* __restrict__ rowptr,
    const int* __restrict__ counts, const int* __restrict__ perm,
    const float* __restrict__ r, float* __restrict__ out) {
    int lane = threadIdx.x & 63;
    int wid = threadIdx.x >> 6;
    int n = blockIdx.x * 4 + wid;
    if (n >= N_NODES) return;
    int g = lane >> 2;
    int q = lane & 3;
    int start = rowptr[n];
    int cnt = counts[n];
    int end = start + cnt;
    float acc[8] = {0, 0, 0, 0, 0, 0, 0, 0};
    for (int i = start + g; i < end; i += 16) {
        int idx = perm[i];
        u16x8 v = *(const u16x8*)&tb[(size_t)idx * 32 + q * 8];
#pragma unroll
        for (int k = 0; k < 8; ++k) acc[k] += bf2f(v[k]);
    }
#pragma unroll
    for (int off = 4; off < 64; off <<= 1)
#pragma unroll
        for (int k = 0; k < 8; ++k) acc[k] += __shfl_xor(acc[k], off, 64);
    if (g == 0) {
        float inv = 1.0f / fmaxf((float)cnt, 1.0f);
        const float4* rp = (const float4*)&r[(size_t)n * 32 + q * 8];
        float4 r0 = rp[0], r1 = rp[1];
        float4 o0 = make_float4(acc[0] * inv + r0.x, acc[1] * inv + r0.y,
                                acc[2] * inv + r0.z, acc[3] * inv + r0.w);
        float4 o1 = make_float4(acc[4] * inv + r1.x, acc[5] * inv + r1.y,
                                acc[6] * inv + r1.z, acc[7] * inv + r1.w);
        float4* op = (float4*)&out[(size_t)n * 32 + q * 8];
        op[0] = o0; op[1] = o1;
    }
}

// ---- MFMA transform: 16 nodes per wave-chunk, 16x16x32 bf16 -------------
// Layer 1: h[16n x 64j] = mfma(mean,W1l) + mfma(x,W1r) (+b1, relu) -> LDS.
// Layer 2: [t|r][16n x 64] = h @ [W2l^T | W2r^T] (+b2 on r).
// A-frag: row=lane&15, k=8*(lane>>4)+e. B-frag: col=lane&15, same k.
// C/D: col=lane&15, row=4*(lane>>4)+reg  [m89-verified].
__global__ __launch_bounds__(256) void transform_mfma_kernel(
    const ushort* __restrict__ xb, const ushort* __restrict__ mb,
    const ushort* __restrict__ wb, const float* __restrict__ b1,
    const float* __restrict__ b2, ushort* __restrict__ tb,
    float* __restrict__ r) {
    __shared__ ushort hlds[4][16 * 72];    // per-wave h tile, padded stride 72
    int lane = threadIdx.x & 63;
    int wid = threadIdx.x >> 6;
    int l15 = lane & 15, lhi = lane >> 4;

    const ushort* w1l = wb;
    const ushort* w1r = wb + 2048;
    const ushort* w2l = wb + 4096;
    const ushort* w2r = wb + 6144;

    bf16x8 B1l[4], B1r[4];                 // layer-1 B frags per j-tile
#pragma unroll
    for (int jt = 0; jt < 4; ++jt) {
        B1l[jt] = *(const bf16x8*)&w1l[(jt * 16 + l15) * 32 + 8 * lhi];
        B1r[jt] = *(const bf16x8*)&w1r[(jt * 16 + l15) * 32 + 8 * lhi];
    }
    bf16x8 B2l[2][2], B2r[2][2];           // [col-tile][k-chunk]
#pragma unroll
    for (int ct = 0; ct < 2; ++ct)
#pragma unroll
        for (int kc = 0; kc < 2; ++kc) {
            B2l[ct][kc] = *(const bf16x8*)&w2l[(ct * 16 + l15) * 64 + kc * 32 + 8 * lhi];
            B2r[ct][kc] = *(const bf16x8*)&w2r[(ct * 16 + l15) * 64 + kc * 32 + 8 * lhi];
        }
    float bias1[4];
#pragma unroll
    for (int jt = 0; jt < 4; ++jt) bias1[jt] = b1[jt * 16 + l15];
    float bias2[2] = { b2[l15], b2[16 + l15] };

    ushort* hl = hlds[wid];

#pragma unroll
    for (int chunk = 0; chunk < 2; ++chunk) {
        int n0 = blockIdx.x * 128 + wid * 32 + chunk * 16;
        int nrow = n0 + l15;
        bf16x8 Am = {}, Ax = {};
        if (nrow < N_NODES) {
            Am = *(const bf16x8*)&mb[(size_t)nrow * 32 + 8 * lhi];
            Ax = *(const bf16x8*)&xb[(size_t)nrow * 32 + 8 * lhi];
        }
#pragma unroll
        for (int jt = 0; jt < 4; ++jt) {
            f32x4 acc = {};
            acc = __builtin_amdgcn_mfma_f32_16x16x32_bf16(Am, B1l[jt], acc, 0, 0, 0);
            acc = __builtin_amdgcn_mfma_f32_16x16x32_bf16(Ax, B1r[jt], acc, 0, 0, 0);
#pragma unroll
            for (int reg = 0; reg < 4; ++reg) {
                float h = fmaxf(acc[reg] + bias1[jt], 0.0f);
                hl[(lhi * 4 + reg) * 72 + jt * 16 + l15] = f2bf(h);
            }
        }
        bf16x8 Ah0 = *(const bf16x8*)&hl[l15 * 72 + 8 * lhi];
        bf16x8 Ah1 = *(const bf16x8*)&hl[l15 * 72 + 32 + 8 * lhi];
#pragma unroll
        for (int ct = 0; ct < 2; ++ct) {
            f32x4 acc = {};
            acc = __builtin_amdgcn_mfma_f32_16x16x32_bf16(Ah0, B2l[ct][0], acc, 0, 0, 0);
            acc = __builtin_amdgcn_mfma_f32_16x16x32_bf16(Ah1, B2l[ct][1], acc, 0, 0, 0);
#pragma unroll
            for (int reg = 0; reg < 4; ++reg) {
                int nr = n0 + lhi * 4 + reg;
                if (nr < N_NODES)
                    tb[(size_t)nr * 32 + ct * 16 + l15] = f2bf(acc[reg]);
            }
        }
#pragma unroll
        for (int ct = 0; ct < 2; ++ct) {
            f32x4 acc = {};
            acc = __builtin_amdgcn_mfma_f32_16x16x32_bf16(Ah0, B2r[ct][0], acc, 0, 0, 0);
            acc = __builtin_amdgcn_mfma_f32_16x16x32_bf16(Ah1, B2r[ct][1], acc, 0, 0, 0);
#pragma unroll
            for (int reg = 0; reg < 4; ++reg) {
                int nr = n0 + lhi * 4 + reg;
                if (nr < N_NODES)
                    r[(size_t)nr * 32 + ct * 16 + l15] = acc[reg] + bias2[ct];
            }
        }
    }
}

// ---- launch -------------------------------------------------------------

extern "C" void kernel_launch(void* const* d_in, const int* in_sizes, int n_in,
                              void* d_out, int out_size, void* d_ws, size_t ws_size,
                              hipStream_t stream) {
    const float* x   = (const float*)d_in[0];
    const float* W1l = (const float*)d_in[1];
    const float* W1r = (const float*)d_in[2];
    const float* b1  = (const float*)d_in[3];
    const float* W2l = (const float*)d_in[4];
    const float* W2r = (const float*)d_in[5];
    const float* b2  = (const float*)d_in[6];
    const int*   ei  = (const int*)d_in[7];   // [2, N_EDGES]
    const int* src = ei;
    const int* dst = ei + N_EDGES;

    char* ws = (char*)d_ws;
    int*    gh     = (int*)ws;               ws += (size_t)NB * NBLK * 4;
    int*    btot   = (int*)ws;               ws += (size_t)(NB + 8) * 4;
    int*    bbase  = (int*)ws;               ws += (size_t)(NB + 8) * 4;
    int*    counts = (int*)ws;               ws += (size_t)N_NODES * 4;
    int*    rowptr = (int*)ws;               ws += (size_t)N_NODES * 4;
    int*    perm   = (int*)ws;               ws += (size_t)N_EDGES * 4;
    uint2*  tmp    = (uint2*)ws;             ws += (size_t)N_EDGES * 8;
    // mb (bf16 mean1) aliases tmp: tmp dead after count_place; mb written after.
    ushort* mb     = (ushort*)tmp;
    ushort* xb     = (ushort*)ws;            ws += (size_t)N_NODES * IN_C * 2;
    ushort* wb     = (ushort*)ws;            ws += (size_t)8192 * 2;
    ushort* tb     = (ushort*)ws;            ws += (size_t)N_NODES * OUT_C * 2;
    float*  r      = (float*)ws;             ws += (size_t)N_NODES * OUT_C * 4;

    dim3 blk(256);
    int ggrid = (N_NODES + 3) / 4;

    cast_x_kernel<<<(N_NODES * IN_C / 8 + 255) / 256, blk, 0, stream>>>(x, xb);
    cast_w_kernel<<<1, blk, 0, stream>>>(W1l, W1r, W2l, W2r, wb);

    bucket_hist_kernel<<<NBLK, blk, 0, stream>>>(dst, gh);
    bucket_scan_kernel<<<NB, blk, 0, stream>>>(gh, btot);
    base_scan_kernel<<<1, 1, 0, stream>>>(btot, bbase);
    bucket_place_kernel<<<NBLK, blk, 0, stream>>>(src, dst, gh, bbase, tmp);
    count_place_kernel<<<NB, dim3(512), 0, stream>>>(tmp, bbase, counts, rowptr, perm);

    gather_mean_kernel<<<ggrid, blk, 0, stream>>>(xb, rowptr, counts, perm, mb);
    transform_mfma_kernel<<<(N_NODES + 127) / 128, blk, 0, stream>>>(
        xb, mb, wb, b1, b2, tb, r);
    gather_final_kernel<<<ggrid, blk, 0, stream>>>(tb, rowptr, counts, perm, r,
                                                   (float*)d_out);
}